// Round 10
// baseline (124.008 us; speedup 1.0000x reference)
//
#include <hip/hip_runtime.h>

// Chamfer distance, B=16 clouds x N=4096 x D=3, fp32, via bf16-split MFMA.
// S_ij by ONE v_mfma_f32_16x16x32_bf16 (K=32, f32x4 acc in VGPRs):
//   A k0-15 = [xh0..2, xl0..2, xh0..2, xl0..2, x2h, x2l, 1, 1]
//   B k0-15 = [-2yh0..2, -2yh0..2, -2yl0..2, -2yl0..2, 1, 1, y2h, y2l]
//   dot = x^2 + y^2 - 2(xh+xl).(yh+yl), all cross terms (err ~3e-4).
// History: R8 96.0 (no-barrier global-B loop: cd_mfma ~30us by subtraction,
//   the only sub-43 kernel ever). R9/R10 fences 137 REGRESSION. R11 min3
//   NEUTRAL. R12 lb(256,5) FAILED. R13-R17 LDS-staged variants: cd_mfma
//   PINNED 42-47us across 3x VALU, 2x MFMA, 4x blocks, 1/4 per-block work.
//   R16 counters: per-CU MFMA-busy 13us + VALU-busy 25us ~= 38/43.7us,
//   occupancy 27% -> pipes busy but NOT overlapping: the per-stage
//   __syncthreads at 2-4 resident blocks/CU serializes everything (barrier
//   drains vmcnt; all waves gated on slowest stage).
// R18: barrier-free streaming. No LDS staging at all: B row-major 32B/pt,
//   each lane streams its own 16B fragments from L2 (lanes 0-31 cover
//   contiguous 1KB per 2 tiles), depth-2 prefetch (8 loads in flight),
//   ZERO __syncthreads in main loop -> waves slip, pipes overlap.
//   Grid (32,16,2)=1024 blocks, row-min only, one atomicAdd per block,
//   2 launches, no reduce/rowpart. Pre-commit: if still ~43us, structure
//   is exonerated -> session floor = fill(43)+overheads; declare next round.

namespace {

constexpr int kB = 16;
constexpr int kN = 4096;
constexpr int kPlane = kB * kN;
constexpr float kScale = 1.0f / (float)(kB * kN);

typedef short bf16x8 __attribute__((ext_vector_type(8)));
typedef float f32x4 __attribute__((ext_vector_type(4)));
typedef unsigned short u16;

__device__ inline u16 bf16_rn(float f) {
  union { float f; unsigned u; } v; v.f = f;
  unsigned r = v.u + 0x7fffu + ((v.u >> 16) & 1u);
  return (u16)(r >> 16);
}
__device__ inline float bf16_f(u16 h) {
  union { unsigned u; float f; } v; v.u = (unsigned)h << 16;
  return v.f;
}
__device__ inline unsigned pk2(u16 lo, u16 hi) {
  return (unsigned)lo | ((unsigned)hi << 16);
}

__global__ void init_out(float* out) { out[0] = 0.0f; }

// One thread per point p: A row and B row (both row-major, 32B at p*32)
// for BOTH inputs. Zeroes out[0]. Layouts as header comment.
__global__ __launch_bounds__(256) void cd_prep(
    const float* __restrict__ pred, const float* __restrict__ targ,
    u16* __restrict__ Apred, u16* __restrict__ Atarg,
    u16* __restrict__ Bpred, u16* __restrict__ Btarg,
    float* __restrict__ out) {
  const int p = blockIdx.x * 256 + threadIdx.x;   // 0..kPlane-1
  if (p == 0) out[0] = 0.0f;
  const u16 one = 0x3F80;

  const float* srcs[2] = {pred, targ};
  u16* adsts[2] = {Apred, Atarg};
  u16* bdsts[2] = {Bpred, Btarg};
#pragma unroll
  for (int which = 0; which < 2; ++which) {
    const float a = srcs[which][3 * p], c = srcs[which][3 * p + 1],
                d = srcs[which][3 * p + 2];
    const u16 ah = bf16_rn(a), ch = bf16_rn(c), dh = bf16_rn(d);
    const u16 al = bf16_rn(a - bf16_f(ah));
    const u16 cl = bf16_rn(c - bf16_f(ch));
    const u16 dl = bf16_rn(d - bf16_f(dh));
    const float s2 = fmaf(a, a, fmaf(c, c, d * d));
    const u16 s2h = bf16_rn(s2);
    const u16 s2l = bf16_rn(s2 - bf16_f(s2h));
    {  // A row
      uint4 w0, w1;
      w0.x = pk2(ah, ch); w0.y = pk2(dh, al); w0.z = pk2(cl, dl); w0.w = pk2(ah, ch);
      w1.x = pk2(dh, al); w1.y = pk2(cl, dl); w1.z = pk2(s2h, s2l); w1.w = pk2(one, one);
      uint4* dst = reinterpret_cast<uint4*>(adsts[which] + (size_t)p * 16);
      dst[0] = w0; dst[1] = w1;
    }
    {  // B row (-2 scale exact in bf16)
      const u16 nah = bf16_rn(-2.0f * bf16_f(ah));
      const u16 nch = bf16_rn(-2.0f * bf16_f(ch));
      const u16 ndh = bf16_rn(-2.0f * bf16_f(dh));
      const u16 nal = bf16_rn(-2.0f * bf16_f(al));
      const u16 ncl = bf16_rn(-2.0f * bf16_f(cl));
      const u16 ndl = bf16_rn(-2.0f * bf16_f(dl));
      uint4 w0, w1;
      w0.x = pk2(nah, nch); w0.y = pk2(ndh, nah); w0.z = pk2(nch, ndh); w0.w = pk2(nal, ncl);
      w1.x = pk2(ndl, nal); w1.y = pk2(ncl, ndl); w1.z = pk2(one, one); w1.w = pk2(s2h, s2l);
      uint4* dst = reinterpret_cast<uint4*>(bdsts[which] + (size_t)p * 16);
      dst[0] = w0; dst[1] = w1;
    }
  }
}

// Block = 4 waves x 32 rows = 128 rows of X (cloud, chunk); each wave
// streams ALL kN opposite points from L2, no LDS, no barriers.
// 16x16x32: A row/col = lane&15, k-group = lane>>4 (groups 2,3 zero ops).
// C/D [m89]: col=lane&15, row=(lane>>4)*4+reg.
__global__ __launch_bounds__(256) void cd_mfma(
    const u16* __restrict__ Apred, const u16* __restrict__ Atarg,
    const u16* __restrict__ Bpred, const u16* __restrict__ Btarg,
    float* __restrict__ out) {
  __shared__ float wsum[4];

  const int t = threadIdx.x;
  const int w = t >> 6, lane = t & 63;
  const int l15 = lane & 15, kg = lane >> 4;   // k-group 0..3
  const bool act = (kg < 2);                   // lanes 32-63: zero operands
  const int g = kg & 1;                        // k-half for active lanes
  const int chunk = blockIdx.x;      // 0..31 -> 128 rows per block
  const int cloud = blockIdx.y;      // 0..15
  const int dir = blockIdx.z;        // 0: pred rows vs targ; 1: swapped
  const u16* __restrict__ A = dir ? Atarg : Apred;
  const u16* __restrict__ B = dir ? Bpred : Btarg;

  // ---- A fragments: rows band+l15 (af0) and band+16+l15 (af1) ----
  const int arow0 = cloud * kN + chunk * 128 + w * 32 + l15;
  union U { uint4 u; bf16x8 v; };
  U af0, af1;
  af0.u = make_uint4(0, 0, 0, 0);
  af1.u = make_uint4(0, 0, 0, 0);
  if (act) {
    af0.u = *reinterpret_cast<const uint4*>(A + (size_t)arow0 * 16 + g * 8);
    af1.u = *reinterpret_cast<const uint4*>(A + (size_t)(arow0 + 16) * 16 + g * 8);
  }

  // ---- B streaming: per-lane 16B fragment addresses, depth-2 prefetch ----
  const char* bb = (const char*)(B + (size_t)cloud * kN * 16);
  const int lofs = l15 * 32 + g * 16;   // byte offset within a 16-pt tile

  // load the two 16-pt tiles starting at point JB into U0,U1 (active lanes)
#define LDF(JB, U0, U1)                                                      \
  if (act) {                                                                 \
    U0.u = *reinterpret_cast<const uint4*>(bb + (size_t)(JB) * 32 + lofs);   \
    U1.u = *reinterpret_cast<const uint4*>(bb + (size_t)(JB) * 32 + 512 + lofs); \
  }

  f32x4 z4;
#pragma unroll
  for (int r = 0; r < 4; ++r) z4[r] = 0.0f;
  float rmin0[4], rmin1[4];
#pragma unroll
  for (int r = 0; r < 4; ++r) { rmin0[r] = 1e30f; rmin1[r] = 1e30f; }

#define CMP(U0, U1)                                                          \
  {                                                                          \
    const f32x4 s00 =                                                        \
        __builtin_amdgcn_mfma_f32_16x16x32_bf16(af0.v, U0.v, z4, 0, 0, 0);   \
    const f32x4 s01 =                                                        \
        __builtin_amdgcn_mfma_f32_16x16x32_bf16(af0.v, U1.v, z4, 0, 0, 0);   \
    const f32x4 s10 =                                                        \
        __builtin_amdgcn_mfma_f32_16x16x32_bf16(af1.v, U0.v, z4, 0, 0, 0);   \
    const f32x4 s11 =                                                        \
        __builtin_amdgcn_mfma_f32_16x16x32_bf16(af1.v, U1.v, z4, 0, 0, 0);   \
    _Pragma("unroll")                                                        \
    for (int r = 0; r < 4; ++r) {                                            \
      rmin0[r] = fminf(rmin0[r], fminf(s00[r], s01[r]));                     \
      rmin1[r] = fminf(rmin1[r], fminf(s10[r], s11[r]));                     \
    }                                                                        \
  }

  U c0a, c0b, c1a, c1b, n0a, n0b, n1a, n1b;
  c0a.u = make_uint4(0, 0, 0, 0); c0b.u = c0a.u;
  c1a.u = c0a.u; c1b.u = c0a.u;
  n0a.u = c0a.u; n0b.u = c0a.u; n1a.u = c0a.u; n1b.u = c0a.u;

  LDF(0, c0a, c0b);
  LDF(32, c1a, c1b);
  // 64 trips x 64 points; wraparound prefetch (re-reads pts 0..63 at the
  // tail: harmless, L2-hot, keeps the loop branch-free).
  for (int jt = 0; jt < 128; jt += 2) {
    const int j2 = ((jt + 2) & 127) * 32;
    const int j3 = ((jt + 3) & 127) * 32;
    LDF(j2, n0a, n0b);
    CMP(c0a, c0b);
    LDF(j3, n1a, n1b);
    CMP(c1a, c1b);
    c0a = n0a; c0b = n0b; c1a = n1a; c1b = n1b;
  }
#undef LDF
#undef CMP

  // Complete row-mins: butterfly over the 16 lanes of each k-group
  // (same rows, different col positions j).
#pragma unroll
  for (int sh = 1; sh < 16; sh <<= 1) {
#pragma unroll
    for (int r = 0; r < 4; ++r) {
      rmin0[r] = fminf(rmin0[r], __shfl_xor(rmin0[r], sh, 64));
      rmin1[r] = fminf(rmin1[r], __shfl_xor(rmin1[r], sh, 64));
    }
  }
  // Lane group kg holds rows kg*4+r (af0: band rows 0-15; af1: 16-31).
  float s = 0.0f;
#pragma unroll
  for (int r = 0; r < 4; ++r) s += rmin0[r] + rmin1[r];
  s = (l15 == 0) ? s : 0.0f;        // one contributor lane per k-group
  s += __shfl_xor(s, 16, 64);
  s += __shfl_xor(s, 32, 64);
  if (lane == 0) wsum[w] = s;
  __syncthreads();
  if (t == 0)
    atomicAdd(out, (wsum[0] + wsum[1] + wsum[2] + wsum[3]) * kScale);
}

// ---------- fallback (small ws): R5-style pk_fma direct kernel ----------
template <int KX>
__global__ __launch_bounds__(256) void chamfer_direct(
    const float* __restrict__ pred, const float* __restrict__ targ,
    float* __restrict__ out) {
  __shared__ float4 tA[128], tB[128];
  const int t = threadIdx.x;
  const int xb = blockIdx.x, b = blockIdx.y, dir = blockIdx.z;
  const float* __restrict__ X = dir ? targ : pred;
  const float* __restrict__ Y = dir ? pred : targ;
  float2 xx2[KX], xy2[KX], xz2[KX];
  float x2[KX], mn[KX];
  const int ibase = b * kN + xb * (256 * KX) + t;
#pragma unroll
  for (int k = 0; k < KX; ++k) {
    const int i = ibase + k * 256;
    const float a = X[3 * i], c = X[3 * i + 1], d = X[3 * i + 2];
    x2[k] = fmaf(a, a, fmaf(c, c, d * d));
    xx2[k] = make_float2(-2.0f * a, -2.0f * a);
    xy2[k] = make_float2(-2.0f * c, -2.0f * c);
    xz2[k] = make_float2(-2.0f * d, -2.0f * d);
    mn[k] = 1e30f;
  }
  for (int t0 = 0; t0 < kN; t0 += 256) {
    __syncthreads();
    if (t < 128) {
      const int j0 = 3 * (b * kN + t0 + 2 * t);
      const float a0 = Y[j0], c0 = Y[j0 + 1], d0 = Y[j0 + 2];
      const float a1 = Y[j0 + 3], c1 = Y[j0 + 4], d1 = Y[j0 + 5];
      tA[t] = make_float4(a0, a1, c0, c1);
      tB[t] = make_float4(d0, d1, fmaf(a0, a0, fmaf(c0, c0, d0 * d0)),
                          fmaf(a1, a1, fmaf(c1, c1, d1 * d1)));
    }
    __syncthreads();
    for (int jj = 0; jj < 128; ++jj) {
      const float4 qa = tA[jj], qb = tB[jj];
      const float2 qx = make_float2(qa.x, qa.y), qy = make_float2(qa.z, qa.w);
      const float2 qz = make_float2(qb.x, qb.y), qw = make_float2(qb.z, qb.w);
#pragma unroll
      for (int k = 0; k < KX; ++k) {
        float2 acc;
        asm("v_pk_fma_f32 %0, %1, %2, %3\n\t"
            "v_pk_fma_f32 %0, %4, %5, %0\n\t"
            "v_pk_fma_f32 %0, %6, %7, %0"
            : "=&v"(acc)
            : "v"(xz2[k]), "v"(qz), "v"(qw), "v"(xy2[k]), "v"(qy),
              "v"(xx2[k]), "v"(qx));
        asm("v_min3_f32 %0, %0, %1, %2" : "+v"(mn[k]) : "v"(acc.x), "v"(acc.y));
      }
    }
  }
  float s = 0.0f;
#pragma unroll
  for (int k = 0; k < KX; ++k) s += x2[k] + mn[k];
  for (int o = 32; o > 0; o >>= 1) s += __shfl_down(s, o, 64);
  __shared__ float wsum[4];
  const int lane = t & 63, wv = t >> 6;
  if (lane == 0) wsum[wv] = s;
  __syncthreads();
  if (t == 0)
    atomicAdd(out, (wsum[0] + wsum[1] + wsum[2] + wsum[3]) * kScale);
}

}  // namespace

extern "C" void kernel_launch(void* const* d_in, const int* in_sizes, int n_in,
                              void* d_out, int out_size, void* d_ws,
                              size_t ws_size, hipStream_t stream) {
  const float* pred = (const float*)d_in[0];
  const float* targ = (const float*)d_in[1];
  float* out = (float*)d_out;

  const size_t needOne = (size_t)kPlane * 16 * sizeof(u16);   // 2 MB each
  if (ws_size >= 4 * needOne) {                               // 8 MB
    u16* Apred = (u16*)d_ws;
    u16* Atarg = (u16*)((char*)d_ws + needOne);
    u16* Bpred = (u16*)((char*)d_ws + 2 * needOne);
    u16* Btarg = (u16*)((char*)d_ws + 3 * needOne);
    cd_prep<<<dim3(kPlane / 256), 256, 0, stream>>>(pred, targ, Apred, Atarg,
                                                    Bpred, Btarg, out);
    cd_mfma<<<dim3(32, kB, 2), 256, 0, stream>>>(Apred, Atarg, Bpred, Btarg,
                                                 out);
  } else {
    init_out<<<dim3(1), dim3(1), 0, stream>>>(out);
    constexpr int KX = 8;
    dim3 grid(kN / (256 * KX), kB, 2);
    chamfer_direct<KX><<<grid, 256, 0, stream>>>(pred, targ, out);
  }
}

// Round 11
// 108.232 us; speedup vs baseline: 1.1458x; 1.1458x over previous
//
#include <hip/hip_runtime.h>

// Chamfer distance, B=16 clouds x N=4096 x D=3, fp32, via bf16-split MFMA.
// S_ij by ONE v_mfma_f32_16x16x32_bf16 (K=32, f32x4 acc in VGPRs):
//   A k0-15 = [xh0..2, xl0..2, xh0..2, xl0..2, x2h, x2l, 1, 1]
//   B k0-15 = [-2yh0..2, -2yh0..2, -2yl0..2, -2yl0..2, 1, 1, y2h, y2l]
//   dot = x^2 + y^2 - 2(xh+xl).(yh+yl), all cross terms (err ~3e-4).
// History: R8 96.0. R9/R10 fences 137 REG. R11 min3 NEUT. R12 lb(256,5)
//   FAILED. R13 100.8. R14 dir-split 43.2/94.5-best. R15 47. R16 43.7.
//   R17 +blocks: mfma ~38 by subtraction, total 106 (reduce overhead).
//   R18 no-LDS streaming: 71.2 REGRESSION (4x L2 traffic + copy VALU) ->
//   LDS staging is worth ~27us; barriers not the pin. Reverted.
//   R16 balance: MFMA-busy 13 + VALU-busy 25 ~= 38/43.7us, occupancy 27%
//   (~2.2 waves/SIMD) -> pipes busy SERIALLY; supply cap 16 waves/CU
//   (1024 blk x 4 waves) + per-tile dep chain (ds_read->MFMA->hazard->fmin).
// R19: two concurrency fixes, staging untouched:
//   (1) wave owns 16 rows (af0 only) -> 8192 waves = 32/CU supply,
//       grid (64,16,2)=2048 blocks, ~60 VGPR (8 waves/SIMD possible);
//   (2) batch-4 inner loop: 4 ds_read -> 4 MFMA -> 16 fmin, MFMA result
//       consumed ~3 issues later (hazard covered by ILP).
//   Pre-commit: if mfma still ~43us, concurrency exhausted -> declare floor.

namespace {

constexpr int kB = 16;
constexpr int kN = 4096;
constexpr int kPlane = kB * kN;
constexpr int kStage = 256;               // points per LDS stage
constexpr int kNS = kN / kStage;          // 16 stages
constexpr float kScale = 1.0f / (float)(kB * kN);

typedef short bf16x8 __attribute__((ext_vector_type(8)));
typedef float f32x4 __attribute__((ext_vector_type(4)));
typedef unsigned short u16;

__device__ inline u16 bf16_rn(float f) {
  union { float f; unsigned u; } v; v.f = f;
  unsigned r = v.u + 0x7fffu + ((v.u >> 16) & 1u);
  return (u16)(r >> 16);
}
__device__ inline float bf16_f(u16 h) {
  union { unsigned u; float f; } v; v.u = (unsigned)h << 16;
  return v.f;
}
__device__ inline unsigned pk2(u16 lo, u16 hi) {
  return (unsigned)lo | ((unsigned)hi << 16);
}

__global__ void init_out(float* out) { out[0] = 0.0f; }

// One thread per point p: A row (row-major 32B at p*32) and B row
// (plane-separated per 256-pt stage: [cloud][stg][khalf][pl] 16B) for BOTH
// inputs. Zeroes out[0].
// A u16[16]: [xh0..2, xl0..2, xh0..2, xl0..2, x2h, x2l, 1, 1]
// B u16[16]: [-2yh0..2, -2yh0..2, -2yl0..2, -2yl0..2, 1, 1, y2h, y2l]
__global__ __launch_bounds__(256) void cd_prep(
    const float* __restrict__ pred, const float* __restrict__ targ,
    u16* __restrict__ Apred, u16* __restrict__ Atarg,
    u16* __restrict__ Bpred, u16* __restrict__ Btarg,
    float* __restrict__ out) {
  const int p = blockIdx.x * 256 + threadIdx.x;   // 0..kPlane-1
  if (p == 0) out[0] = 0.0f;
  const int cloud = p >> 12, q = p & (kN - 1);
  const int stg = q >> 8, pl = q & (kStage - 1);
  // u16 units: cloud 65536 (128KB), stage 4096 (8KB), khalf 2048 (4KB)
  const size_t boff = (size_t)cloud * 65536 + (size_t)stg * 4096 + (size_t)pl * 8;
  const u16 one = 0x3F80;

  const float* srcs[2] = {pred, targ};
  u16* adsts[2] = {Apred, Atarg};
  u16* bdsts[2] = {Bpred, Btarg};
#pragma unroll
  for (int which = 0; which < 2; ++which) {
    const float a = srcs[which][3 * p], c = srcs[which][3 * p + 1],
                d = srcs[which][3 * p + 2];
    const u16 ah = bf16_rn(a), ch = bf16_rn(c), dh = bf16_rn(d);
    const u16 al = bf16_rn(a - bf16_f(ah));
    const u16 cl = bf16_rn(c - bf16_f(ch));
    const u16 dl = bf16_rn(d - bf16_f(dh));
    const float s2 = fmaf(a, a, fmaf(c, c, d * d));
    const u16 s2h = bf16_rn(s2);
    const u16 s2l = bf16_rn(s2 - bf16_f(s2h));
    {  // A row
      uint4 w0, w1;
      w0.x = pk2(ah, ch); w0.y = pk2(dh, al); w0.z = pk2(cl, dl); w0.w = pk2(ah, ch);
      w1.x = pk2(dh, al); w1.y = pk2(cl, dl); w1.z = pk2(s2h, s2l); w1.w = pk2(one, one);
      uint4* dst = reinterpret_cast<uint4*>(adsts[which] + (size_t)p * 16);
      dst[0] = w0; dst[1] = w1;
    }
    {  // B row (-2 scale exact in bf16)
      const u16 nah = bf16_rn(-2.0f * bf16_f(ah));
      const u16 nch = bf16_rn(-2.0f * bf16_f(ch));
      const u16 ndh = bf16_rn(-2.0f * bf16_f(dh));
      const u16 nal = bf16_rn(-2.0f * bf16_f(al));
      const u16 ncl = bf16_rn(-2.0f * bf16_f(cl));
      const u16 ndl = bf16_rn(-2.0f * bf16_f(dl));
      uint4 w0, w1;
      w0.x = pk2(nah, nch); w0.y = pk2(ndh, nah); w0.z = pk2(nch, ndh); w0.w = pk2(nal, ncl);
      w1.x = pk2(ndl, nal); w1.y = pk2(ncl, ndl); w1.z = pk2(one, one); w1.w = pk2(s2h, s2l);
      *reinterpret_cast<uint4*>(bdsts[which] + boff) = w0;
      *reinterpret_cast<uint4*>(bdsts[which] + boff + 2048) = w1;
    }
  }
}

// Block = 4 waves x 16 rows = 64 rows of X (cloud, chunk); scans all kN
// opposite points staged through double-buffered LDS via global_load_lds.
// 16x16x32: A row/col = lane&15, k-group = lane>>4 (groups 2,3 zero ops).
// C/D [m89]: col=lane&15, row=(lane>>4)*4+reg.
// Batch-4 inner loop: 4 ds_read -> 4 MFMA -> 16 fmin (hazard hidden by ILP).
__global__ __launch_bounds__(256) void cd_mfma(
    const u16* __restrict__ Apred, const u16* __restrict__ Atarg,
    const u16* __restrict__ Bpred, const u16* __restrict__ Btarg,
    float* __restrict__ out) {
  __shared__ uint4 Blds4[1028];   // 16 KB dbuf (2x8KB) + 16B zero scratch
  __shared__ float wsum[4];

  const int t = threadIdx.x;
  const int w = t >> 6, lane = t & 63;
  const int l15 = lane & 15, kg = lane >> 4;   // k-group 0..3
  const bool act = (kg < 2);                   // lanes 32-63: zero operands
  const int g = kg & 1;                        // k-half for active lanes
  const int chunk = blockIdx.x;      // 0..63 -> 64 rows per block
  const int cloud = blockIdx.y;      // 0..15
  const int dir = blockIdx.z;        // 0: pred rows vs targ; 1: swapped
  const u16* __restrict__ A = dir ? Atarg : Apred;
  const u16* __restrict__ B = dir ? Bpred : Btarg;

  // ---- A fragment: wave's 16 rows, lane l15 -> row, g -> k-half ----
  const int arow0 = cloud * kN + chunk * 64 + w * 16 + l15;
  union U { uint4 u; bf16x8 v; };
  U af0;
  af0.u = make_uint4(0, 0, 0, 0);
  if (act)
    af0.u = *reinterpret_cast<const uint4*>(A + (size_t)arow0 * 16 + g * 8);

  // ---- staging: linear copy, 2 x global_load_lds(16B) per thread/stage ----
  const char* bcl = (const char*)B + (size_t)cloud * 131072;   // 128KB/cloud
  char* ldsbase = (char*)Blds4;
#define STAGE(st, buf)                                                        \
  {                                                                           \
    const char* _src = bcl + (size_t)(st) * 8192;                             \
    char* _dst = ldsbase + (buf) * 8192;                                      \
    _Pragma("unroll")                                                         \
    for (int i = 0; i < 2; ++i) {                                             \
      __builtin_amdgcn_global_load_lds(                                       \
          (const __attribute__((address_space(1))) void*)(_src +              \
              ((w * 2 + i) * 64 + lane) * 16),                                \
          (__attribute__((address_space(3))) void*)(_dst + (w * 2 + i) * 1024),\
          16, 0, 0);                                                          \
    }                                                                         \
  }

  // B read addressing: active lanes walk their k-half plane; zero lanes
  // broadcast-read the 16B zero scratch (stride 0, no conflict).
  const int rb0 = act ? (g * 4096 + l15 * 16) : 16384;
  const int rstep = act ? 256 : 0;       // bytes per 16-pt tile
  const int bufstep = act ? 8192 : 0;

  f32x4 z4;
#pragma unroll
  for (int r = 0; r < 4; ++r) z4[r] = 0.0f;
  float rmin[4];
#pragma unroll
  for (int r = 0; r < 4; ++r) rmin[r] = 1e30f;

  STAGE(0, 0);
  if (t == 0) Blds4[1024] = make_uint4(0, 0, 0, 0);   // zero scratch
  __syncthreads();   // buf0 + scratch ready

  for (int st = 0; st < kNS; ++st) {
    if (st < kNS - 1) STAGE(st + 1, (st + 1) & 1);
    const char* pb = ldsbase + rb0 + (st & 1) * bufstep;
#pragma unroll
    for (int bt = 0; bt < kStage / 64; ++bt) {   // 4 batches of 4 tiles
      U b0, b1, b2, b3;
      b0.u = *reinterpret_cast<const uint4*>(pb);
      b1.u = *reinterpret_cast<const uint4*>(pb + rstep);
      b2.u = *reinterpret_cast<const uint4*>(pb + 2 * rstep);
      b3.u = *reinterpret_cast<const uint4*>(pb + 3 * rstep);
      pb += 4 * rstep;
      const f32x4 s0 =
          __builtin_amdgcn_mfma_f32_16x16x32_bf16(af0.v, b0.v, z4, 0, 0, 0);
      const f32x4 s1 =
          __builtin_amdgcn_mfma_f32_16x16x32_bf16(af0.v, b1.v, z4, 0, 0, 0);
      const f32x4 s2 =
          __builtin_amdgcn_mfma_f32_16x16x32_bf16(af0.v, b2.v, z4, 0, 0, 0);
      const f32x4 s3 =
          __builtin_amdgcn_mfma_f32_16x16x32_bf16(af0.v, b3.v, z4, 0, 0, 0);
#pragma unroll
      for (int r = 0; r < 4; ++r) {
        const float m01 = fminf(s0[r], s1[r]);
        const float m23 = fminf(s2[r], s3[r]);
        rmin[r] = fminf(rmin[r], fminf(m01, m23));
      }
    }
    __syncthreads();   // stage loads landed; compute done before overwrite
  }
#undef STAGE

  // Complete row-mins: butterfly over the 16 lanes of each k-group
  // (same rows, different cols j).
#pragma unroll
  for (int sh = 1; sh < 16; sh <<= 1) {
#pragma unroll
    for (int r = 0; r < 4; ++r)
      rmin[r] = fminf(rmin[r], __shfl_xor(rmin[r], sh, 64));
  }
  // Lane group kg holds rows kg*4+r of the wave's 16-row band.
  float s = 0.0f;
#pragma unroll
  for (int r = 0; r < 4; ++r) s += rmin[r];
  s = (l15 == 0) ? s : 0.0f;        // one contributor lane per k-group
  s += __shfl_xor(s, 16, 64);
  s += __shfl_xor(s, 32, 64);
  if (lane == 0) wsum[w] = s;
  __syncthreads();
  if (t == 0)
    atomicAdd(out, (wsum[0] + wsum[1] + wsum[2] + wsum[3]) * kScale);
}

// ---------- fallback (small ws): R5-style pk_fma direct kernel ----------
template <int KX>
__global__ __launch_bounds__(256) void chamfer_direct(
    const float* __restrict__ pred, const float* __restrict__ targ,
    float* __restrict__ out) {
  __shared__ float4 tA[128], tB[128];
  const int t = threadIdx.x;
  const int xb = blockIdx.x, b = blockIdx.y, dir = blockIdx.z;
  const float* __restrict__ X = dir ? targ : pred;
  const float* __restrict__ Y = dir ? pred : targ;
  float2 xx2[KX], xy2[KX], xz2[KX];
  float x2[KX], mn[KX];
  const int ibase = b * kN + xb * (256 * KX) + t;
#pragma unroll
  for (int k = 0; k < KX; ++k) {
    const int i = ibase + k * 256;
    const float a = X[3 * i], c = X[3 * i + 1], d = X[3 * i + 2];
    x2[k] = fmaf(a, a, fmaf(c, c, d * d));
    xx2[k] = make_float2(-2.0f * a, -2.0f * a);
    xy2[k] = make_float2(-2.0f * c, -2.0f * c);
    xz2[k] = make_float2(-2.0f * d, -2.0f * d);
    mn[k] = 1e30f;
  }
  for (int t0 = 0; t0 < kN; t0 += 256) {
    __syncthreads();
    if (t < 128) {
      const int j0 = 3 * (b * kN + t0 + 2 * t);
      const float a0 = Y[j0], c0 = Y[j0 + 1], d0 = Y[j0 + 2];
      const float a1 = Y[j0 + 3], c1 = Y[j0 + 4], d1 = Y[j0 + 5];
      tA[t] = make_float4(a0, a1, c0, c1);
      tB[t] = make_float4(d0, d1, fmaf(a0, a0, fmaf(c0, c0, d0 * d0)),
                          fmaf(a1, a1, fmaf(c1, c1, d1 * d1)));
    }
    __syncthreads();
    for (int jj = 0; jj < 128; ++jj) {
      const float4 qa = tA[jj], qb = tB[jj];
      const float2 qx = make_float2(qa.x, qa.y), qy = make_float2(qa.z, qa.w);
      const float2 qz = make_float2(qb.x, qb.y), qw = make_float2(qb.z, qb.w);
#pragma unroll
      for (int k = 0; k < KX; ++k) {
        float2 acc;
        asm("v_pk_fma_f32 %0, %1, %2, %3\n\t"
            "v_pk_fma_f32 %0, %4, %5, %0\n\t"
            "v_pk_fma_f32 %0, %6, %7, %0"
            : "=&v"(acc)
            : "v"(xz2[k]), "v"(qz), "v"(qw), "v"(xy2[k]), "v"(qy),
              "v"(xx2[k]), "v"(qx));
        asm("v_min3_f32 %0, %0, %1, %2" : "+v"(mn[k]) : "v"(acc.x), "v"(acc.y));
      }
    }
  }
  float s = 0.0f;
#pragma unroll
  for (int k = 0; k < KX; ++k) s += x2[k] + mn[k];
  for (int o = 32; o > 0; o >>= 1) s += __shfl_down(s, o, 64);
  __shared__ float wsum[4];
  const int lane = t & 63, wv = t >> 6;
  if (lane == 0) wsum[wv] = s;
  __syncthreads();
  if (t == 0)
    atomicAdd(out, (wsum[0] + wsum[1] + wsum[2] + wsum[3]) * kScale);
}

}  // namespace

extern "C" void kernel_launch(void* const* d_in, const int* in_sizes, int n_in,
                              void* d_out, int out_size, void* d_ws,
                              size_t ws_size, hipStream_t stream) {
  const float* pred = (const float*)d_in[0];
  const float* targ = (const float*)d_in[1];
  float* out = (float*)d_out;

  const size_t needOne = (size_t)kPlane * 16 * sizeof(u16);   // 2 MB each
  if (ws_size >= 4 * needOne) {                               // 8 MB
    u16* Apred = (u16*)d_ws;
    u16* Atarg = (u16*)((char*)d_ws + needOne);
    u16* Bpred = (u16*)((char*)d_ws + 2 * needOne);
    u16* Btarg = (u16*)((char*)d_ws + 3 * needOne);
    cd_prep<<<dim3(kPlane / 256), 256, 0, stream>>>(pred, targ, Apred, Atarg,
                                                    Bpred, Btarg, out);
    cd_mfma<<<dim3(64, kB, 2), 256, 0, stream>>>(Apred, Atarg, Bpred, Btarg,
                                                 out);
  } else {
    init_out<<<dim3(1), dim3(1), 0, stream>>>(out);
    constexpr int KX = 8;
    dim3 grid(kN / (256 * KX), kB, 2);
    chamfer_direct<KX><<<grid, 256, 0, stream>>>(pred, targ, out);
  }
}

// Round 12
// 103.063 us; speedup vs baseline: 1.2032x; 1.0502x over previous
//
#include <hip/hip_runtime.h>

// Chamfer distance, B=16 clouds x N=4096 x D=3, fp32, via bf16-split MFMA.
// S_ij by ONE v_mfma_f32_16x16x32_bf16 (K=32, f32x4 acc in VGPRs):
//   A k0-15 = [xh0..2, xl0..2, xh0..2, xl0..2, x2h, x2l, 1, 1]
//   B k0-15 = [-2yh0..2, -2yh0..2, -2yl0..2, -2yl0..2, 1, 1, y2h, y2l]
//   dot = x^2 + y^2 - 2(xh+xl).(yh+yl), err ~3e-4. k16-31 zero (lanes 32-63
//   read a zero LDS scratch, stride 0).
// History: R8 96.0. R9/R10 fences 137 REG. R11 NEUT. R12 FAILED. R13 100.8.
//   R14 43.2/94.5-best. R15 47. R16 43.7 (2 MFMA/ds_read, 131MB staging).
//   R17 106 (reduce overhead). R18 no-LDS 71.2 REG (4x L2). R19 64-row
//   waves 56.2 REG (1 MFMA/ds_read, 262MB staging) despite occupancy 42%.
//   RANKING: MFMA-per-staged-byte is the variable; occupancy is not.
//   Model: per-CU MFMA floor ~16.6us (8192 x 4.85cyc, shared matrix pipe);
//   R16 pays 43.7 because per-tile VALU+LDS (~36cyc) > MFMA (~10cyc).
// R20: R16 + 4 A-frags (wave owns 64 rows: af0..3 at +0,+16,+32,+48).
//   Per tile: 1 ds_read_b128 -> 4 MFMA -> 16 fmin (MFMA is now the pole).
//   Block = 4 waves x 64 = 256 rows; grid (16,16,2) = 512 blocks; staging
//   65MB; 8 stages (kStage=512, 32KB dbuf). Everything else R16-verbatim.
//   Pre-commit: 25-30us => MFMA-bound confirmed (next: halve MFMA work);
//   ~43us => amortization exhausted.

namespace {

constexpr int kB = 16;
constexpr int kN = 4096;
constexpr int kPlane = kB * kN;
constexpr int kStage = 512;               // points per LDS stage
constexpr int kNS = kN / kStage;          // 8 stages
constexpr float kScale = 1.0f / (float)(kB * kN);

typedef short bf16x8 __attribute__((ext_vector_type(8)));
typedef float f32x4 __attribute__((ext_vector_type(4)));
typedef unsigned short u16;

__device__ inline u16 bf16_rn(float f) {
  union { float f; unsigned u; } v; v.f = f;
  unsigned r = v.u + 0x7fffu + ((v.u >> 16) & 1u);
  return (u16)(r >> 16);
}
__device__ inline float bf16_f(u16 h) {
  union { unsigned u; float f; } v; v.u = (unsigned)h << 16;
  return v.f;
}
__device__ inline unsigned pk2(u16 lo, u16 hi) {
  return (unsigned)lo | ((unsigned)hi << 16);
}

__global__ void init_out(float* out) { out[0] = 0.0f; }

// One thread per point p: A row (row-major 32B at p*32) and B row
// (plane-separated per 512-pt stage: [cloud][stg][khalf][pl] 16B) for BOTH
// inputs. Zeroes out[0].
__global__ __launch_bounds__(256) void cd_prep(
    const float* __restrict__ pred, const float* __restrict__ targ,
    u16* __restrict__ Apred, u16* __restrict__ Atarg,
    u16* __restrict__ Bpred, u16* __restrict__ Btarg,
    float* __restrict__ out) {
  const int p = blockIdx.x * 256 + threadIdx.x;   // 0..kPlane-1
  if (p == 0) out[0] = 0.0f;
  const int cloud = p >> 12, q = p & (kN - 1);
  const int stg = q >> 9, pl = q & (kStage - 1);
  // u16 units: cloud 65536 (128KB), stage 8192 (16KB), khalf 4096 (8KB)
  const size_t boff = (size_t)cloud * 65536 + (size_t)stg * 8192 + (size_t)pl * 8;
  const u16 one = 0x3F80;

  const float* srcs[2] = {pred, targ};
  u16* adsts[2] = {Apred, Atarg};
  u16* bdsts[2] = {Bpred, Btarg};
#pragma unroll
  for (int which = 0; which < 2; ++which) {
    const float a = srcs[which][3 * p], c = srcs[which][3 * p + 1],
                d = srcs[which][3 * p + 2];
    const u16 ah = bf16_rn(a), ch = bf16_rn(c), dh = bf16_rn(d);
    const u16 al = bf16_rn(a - bf16_f(ah));
    const u16 cl = bf16_rn(c - bf16_f(ch));
    const u16 dl = bf16_rn(d - bf16_f(dh));
    const float s2 = fmaf(a, a, fmaf(c, c, d * d));
    const u16 s2h = bf16_rn(s2);
    const u16 s2l = bf16_rn(s2 - bf16_f(s2h));
    {  // A row
      uint4 w0, w1;
      w0.x = pk2(ah, ch); w0.y = pk2(dh, al); w0.z = pk2(cl, dl); w0.w = pk2(ah, ch);
      w1.x = pk2(dh, al); w1.y = pk2(cl, dl); w1.z = pk2(s2h, s2l); w1.w = pk2(one, one);
      uint4* dst = reinterpret_cast<uint4*>(adsts[which] + (size_t)p * 16);
      dst[0] = w0; dst[1] = w1;
    }
    {  // B row (-2 scale exact in bf16)
      const u16 nah = bf16_rn(-2.0f * bf16_f(ah));
      const u16 nch = bf16_rn(-2.0f * bf16_f(ch));
      const u16 ndh = bf16_rn(-2.0f * bf16_f(dh));
      const u16 nal = bf16_rn(-2.0f * bf16_f(al));
      const u16 ncl = bf16_rn(-2.0f * bf16_f(cl));
      const u16 ndl = bf16_rn(-2.0f * bf16_f(dl));
      uint4 w0, w1;
      w0.x = pk2(nah, nch); w0.y = pk2(ndh, nah); w0.z = pk2(nch, ndh); w0.w = pk2(nal, ncl);
      w1.x = pk2(ndl, nal); w1.y = pk2(ncl, ndl); w1.z = pk2(one, one); w1.w = pk2(s2h, s2l);
      *reinterpret_cast<uint4*>(bdsts[which] + boff) = w0;
      *reinterpret_cast<uint4*>(bdsts[which] + boff + 4096) = w1;
    }
  }
}

// Block = 4 waves x 64 rows = 256 rows of X (cloud, chunk); scans all kN
// opposite points staged through double-buffered LDS via global_load_lds.
// 16x16x32: A row/col = lane&15, k-group = lane>>4 (groups 2,3 zero ops).
// C/D [m89]: col=lane&15, row=(lane>>4)*4+reg.
// Per 16-pt tile: 1 ds_read_b128 -> 4 MFMA (af0..3) -> 16 fmin.
__global__ __launch_bounds__(256) void cd_mfma(
    const u16* __restrict__ Apred, const u16* __restrict__ Atarg,
    const u16* __restrict__ Bpred, const u16* __restrict__ Btarg,
    float* __restrict__ out) {
  __shared__ uint4 Blds4[2049];   // 32 KB dbuf (2x16KB) + 16B zero scratch
  __shared__ float wsum[4];

  const int t = threadIdx.x;
  const int w = t >> 6, lane = t & 63;
  const int l15 = lane & 15, kg = lane >> 4;   // k-group 0..3
  const bool act = (kg < 2);                   // lanes 32-63: zero operands
  const int g = kg & 1;                        // k-half for active lanes
  const int chunk = blockIdx.x;      // 0..15 -> 256 rows per block
  const int cloud = blockIdx.y;      // 0..15
  const int dir = blockIdx.z;        // 0: pred rows vs targ; 1: swapped
  const u16* __restrict__ A = dir ? Atarg : Apred;
  const u16* __restrict__ B = dir ? Bpred : Btarg;

  // ---- A fragments: wave's 64 rows as 4 x 16-row tiles ----
  const int arow0 = cloud * kN + chunk * 256 + w * 64 + l15;
  union U { uint4 u; bf16x8 v; };
  U af[4];
#pragma unroll
  for (int o = 0; o < 4; ++o) af[o].u = make_uint4(0, 0, 0, 0);
  if (act) {
#pragma unroll
    for (int o = 0; o < 4; ++o)
      af[o].u = *reinterpret_cast<const uint4*>(
          A + (size_t)(arow0 + o * 16) * 16 + g * 8);
  }

  // ---- staging: linear copy, 4 x global_load_lds(16B) per thread/stage ----
  const char* bcl = (const char*)B + (size_t)cloud * 131072;   // 128KB/cloud
  char* ldsbase = (char*)Blds4;
#define STAGE(st, buf)                                                        \
  {                                                                           \
    const char* _src = bcl + (size_t)(st) * 16384;                            \
    char* _dst = ldsbase + (buf) * 16384;                                     \
    _Pragma("unroll")                                                         \
    for (int i = 0; i < 4; ++i) {                                             \
      __builtin_amdgcn_global_load_lds(                                       \
          (const __attribute__((address_space(1))) void*)(_src +              \
              ((w * 4 + i) * 64 + lane) * 16),                                \
          (__attribute__((address_space(3))) void*)(_dst + (w * 4 + i) * 1024),\
          16, 0, 0);                                                          \
    }                                                                         \
  }

  // B read addressing: active lanes walk their k-half plane; zero lanes
  // broadcast-read the 16B zero scratch (stride 0, no conflict).
  const int rb0 = act ? (g * 8192 + l15 * 16) : 32768;
  const int rstep = act ? 256 : 0;       // bytes per 16-pt tile
  const int bufstep = act ? 16384 : 0;

  f32x4 z4;
#pragma unroll
  for (int r = 0; r < 4; ++r) z4[r] = 0.0f;
  float rmin[4][4];
#pragma unroll
  for (int o = 0; o < 4; ++o)
#pragma unroll
    for (int r = 0; r < 4; ++r) rmin[o][r] = 1e30f;

  STAGE(0, 0);
  if (t == 0) Blds4[2048] = make_uint4(0, 0, 0, 0);   // zero scratch
  __syncthreads();   // buf0 + scratch ready

  for (int st = 0; st < kNS; ++st) {
    if (st < kNS - 1) STAGE(st + 1, (st + 1) & 1);
    const char* pb = ldsbase + rb0 + (st & 1) * bufstep;
#pragma unroll 4
    for (int jt = 0; jt < kStage / 16; ++jt) {   // 32 tiles of 16 cols
      U bu;
      bu.u = *reinterpret_cast<const uint4*>(pb);
      pb += rstep;
      const f32x4 s0 =
          __builtin_amdgcn_mfma_f32_16x16x32_bf16(af[0].v, bu.v, z4, 0, 0, 0);
      const f32x4 s1 =
          __builtin_amdgcn_mfma_f32_16x16x32_bf16(af[1].v, bu.v, z4, 0, 0, 0);
      const f32x4 s2 =
          __builtin_amdgcn_mfma_f32_16x16x32_bf16(af[2].v, bu.v, z4, 0, 0, 0);
      const f32x4 s3 =
          __builtin_amdgcn_mfma_f32_16x16x32_bf16(af[3].v, bu.v, z4, 0, 0, 0);
#pragma unroll
      for (int r = 0; r < 4; ++r) {
        rmin[0][r] = fminf(rmin[0][r], s0[r]);
        rmin[1][r] = fminf(rmin[1][r], s1[r]);
        rmin[2][r] = fminf(rmin[2][r], s2[r]);
        rmin[3][r] = fminf(rmin[3][r], s3[r]);
      }
    }
    __syncthreads();   // stage loads landed; compute done before overwrite
  }
#undef STAGE

  // Complete row-mins: butterfly over the 16 lanes of each k-group.
#pragma unroll
  for (int sh = 1; sh < 16; sh <<= 1) {
#pragma unroll
    for (int o = 0; o < 4; ++o)
#pragma unroll
      for (int r = 0; r < 4; ++r)
        rmin[o][r] = fminf(rmin[o][r], __shfl_xor(rmin[o][r], sh, 64));
  }
  // Lane group kg holds rows o*16 + kg*4 + r of the wave's 64-row band.
  float s = 0.0f;
#pragma unroll
  for (int o = 0; o < 4; ++o)
#pragma unroll
    for (int r = 0; r < 4; ++r) s += rmin[o][r];
  s = (l15 == 0) ? s : 0.0f;        // one contributor lane per k-group
  s += __shfl_xor(s, 16, 64);
  s += __shfl_xor(s, 32, 64);
  if (lane == 0) wsum[w] = s;
  __syncthreads();
  if (t == 0)
    atomicAdd(out, (wsum[0] + wsum[1] + wsum[2] + wsum[3]) * kScale);
}

// ---------- fallback (small ws): R5-style pk_fma direct kernel ----------
template <int KX>
__global__ __launch_bounds__(256) void chamfer_direct(
    const float* __restrict__ pred, const float* __restrict__ targ,
    float* __restrict__ out) {
  __shared__ float4 tA[128], tB[128];
  const int t = threadIdx.x;
  const int xb = blockIdx.x, b = blockIdx.y, dir = blockIdx.z;
  const float* __restrict__ X = dir ? targ : pred;
  const float* __restrict__ Y = dir ? pred : targ;
  float2 xx2[KX], xy2[KX], xz2[KX];
  float x2[KX], mn[KX];
  const int ibase = b * kN + xb * (256 * KX) + t;
#pragma unroll
  for (int k = 0; k < KX; ++k) {
    const int i = ibase + k * 256;
    const float a = X[3 * i], c = X[3 * i + 1], d = X[3 * i + 2];
    x2[k] = fmaf(a, a, fmaf(c, c, d * d));
    xx2[k] = make_float2(-2.0f * a, -2.0f * a);
    xy2[k] = make_float2(-2.0f * c, -2.0f * c);
    xz2[k] = make_float2(-2.0f * d, -2.0f * d);
    mn[k] = 1e30f;
  }
  for (int t0 = 0; t0 < kN; t0 += 256) {
    __syncthreads();
    if (t < 128) {
      const int j0 = 3 * (b * kN + t0 + 2 * t);
      const float a0 = Y[j0], c0 = Y[j0 + 1], d0 = Y[j0 + 2];
      const float a1 = Y[j0 + 3], c1 = Y[j0 + 4], d1 = Y[j0 + 5];
      tA[t] = make_float4(a0, a1, c0, c1);
      tB[t] = make_float4(d0, d1, fmaf(a0, a0, fmaf(c0, c0, d0 * d0)),
                          fmaf(a1, a1, fmaf(c1, c1, d1 * d1)));
    }
    __syncthreads();
    for (int jj = 0; jj < 128; ++jj) {
      const float4 qa = tA[jj], qb = tB[jj];
      const float2 qx = make_float2(qa.x, qa.y), qy = make_float2(qa.z, qa.w);
      const float2 qz = make_float2(qb.x, qb.y), qw = make_float2(qb.z, qb.w);
#pragma unroll
      for (int k = 0; k < KX; ++k) {
        float2 acc;
        asm("v_pk_fma_f32 %0, %1, %2, %3\n\t"
            "v_pk_fma_f32 %0, %4, %5, %0\n\t"
            "v_pk_fma_f32 %0, %6, %7, %0"
            : "=&v"(acc)
            : "v"(xz2[k]), "v"(qz), "v"(qw), "v"(xy2[k]), "v"(qy),
              "v"(xx2[k]), "v"(qx));
        asm("v_min3_f32 %0, %0, %1, %2" : "+v"(mn[k]) : "v"(acc.x), "v"(acc.y));
      }
    }
  }
  float s = 0.0f;
#pragma unroll
  for (int k = 0; k < KX; ++k) s += x2[k] + mn[k];
  for (int o = 32; o > 0; o >>= 1) s += __shfl_down(s, o, 64);
  __shared__ float wsum[4];
  const int lane = t & 63, wv = t >> 6;
  if (lane == 0) wsum[wv] = s;
  __syncthreads();
  if (t == 0)
    atomicAdd(out, (wsum[0] + wsum[1] + wsum[2] + wsum[3]) * kScale);
}

}  // namespace

extern "C" void kernel_launch(void* const* d_in, const int* in_sizes, int n_in,
                              void* d_out, int out_size, void* d_ws,
                              size_t ws_size, hipStream_t stream) {
  const float* pred = (const float*)d_in[0];
  const float* targ = (const float*)d_in[1];
  float* out = (float*)d_out;

  const size_t needOne = (size_t)kPlane * 16 * sizeof(u16);   // 2 MB each
  if (ws_size >= 4 * needOne) {                               // 8 MB
    u16* Apred = (u16*)d_ws;
    u16* Atarg = (u16*)((char*)d_ws + needOne);
    u16* Bpred = (u16*)((char*)d_ws + 2 * needOne);
    u16* Btarg = (u16*)((char*)d_ws + 3 * needOne);
    cd_prep<<<dim3(kPlane / 256), 256, 0, stream>>>(pred, targ, Apred, Atarg,
                                                    Bpred, Btarg, out);
    cd_mfma<<<dim3(16, kB, 2), 256, 0, stream>>>(Apred, Atarg, Bpred, Btarg,
                                                 out);
  } else {
    init_out<<<dim3(1), dim3(1), 0, stream>>>(out);
    constexpr int KX = 8;
    dim3 grid(kN / (256 * KX), kB, 2);
    chamfer_direct<KX><<<grid, 256, 0, stream>>>(pred, targ, out);
  }
}

// Round 13
// 99.788 us; speedup vs baseline: 1.2427x; 1.0328x over previous
//
#include <hip/hip_runtime.h>

// Chamfer distance, B=16 clouds x N=4096 x D=3, fp32, via bf16-split MFMA.
// R21: S_ij by ONE v_mfma_f32_32x32x16_bf16 (K=16 exact, f32x16 acc):
//   A k0-15 = [xh0..2, xl0..2, xh0..2, x2h, x2l, 1, 1, xl0..2]
//   B k0-15 = [-2yh0..2, -2yh0..2, -2yl0..2, 1, 1, y2h, y2l, -2yl0..2]
//   dot = x^2+y^2-2(xh+xl).(yh+yl), all cross terms (R8-verified pairing).
// History: R8 96.0 best-3-launch. R14 94.5 best (dual-pass 32x32, fused
//   dequant). R15 47 / R16 43.7 / R20 46 (prep-once+gload_lds, 16x16).
//   R17 j-slice 4x: no gain. R18 no-LDS: 71 REG. R19 hi-occupancy: 56 REG.
// ACCOUNTING (R15 counters): VALU-busy 21.6us + MFMA-busy 5.6us = 27us of
//   issue in 47us; ~20us is STALL at occupancy 24% (<2 waves/SIMD, 33KB
//   LDS). VALU-busy matches irreducible min-work (32 ops/1024 entries).
//   No round yet combined minimal per-entry work AND >=5 blocks/CU.
// R21 = R15 economy at R19 occupancy: 32x32x16 (no zero lanes, 16 acc regs
//   per 1024 entries), prep-once, gload_lds staging, kJS=2 slicing with
//   kStage=256 -> LDS 16KB (9 blocks/CU allowed), grid 2048 = 8/CU wanted.
//   Slice-partial row-mins -> rowpart (1MB plain stores), cd_reduce folds.
//   Pre-commit: 40-47us again => envelope immovable, declare floor.

namespace {

constexpr int kB = 16;
constexpr int kN = 4096;
constexpr int kPlane = kB * kN;
constexpr int kJS = 2;                    // j-slices
constexpr int kStage = 256;               // points per LDS stage
constexpr int kNS = (kN / kJS) / kStage;  // 8 stages per slice
constexpr float kScale = 1.0f / (float)(kB * kN);

typedef short bf16x8 __attribute__((ext_vector_type(8)));
typedef float f32x16 __attribute__((ext_vector_type(16)));
typedef unsigned short u16;

__device__ inline u16 bf16_rn(float f) {
  union { float f; unsigned u; } v; v.f = f;
  unsigned r = v.u + 0x7fffu + ((v.u >> 16) & 1u);
  return (u16)(r >> 16);
}
__device__ inline float bf16_f(u16 h) {
  union { unsigned u; float f; } v; v.u = (unsigned)h << 16;
  return v.f;
}
__device__ inline unsigned pk2(u16 lo, u16 hi) {
  return (unsigned)lo | ((unsigned)hi << 16);
}

__global__ void init_out(float* out) { out[0] = 0.0f; }

// One thread per point p: A row (row-major 32B at p*32) and B row
// (plane-separated per 256-pt stage: [cloud][stg][khalf][pl] 16B) for BOTH
// inputs. Zeroes out[0]. K=16 layouts (R8-verified pairing).
__global__ __launch_bounds__(256) void cd_prep(
    const float* __restrict__ pred, const float* __restrict__ targ,
    u16* __restrict__ Apred, u16* __restrict__ Atarg,
    u16* __restrict__ Bpred, u16* __restrict__ Btarg,
    float* __restrict__ out) {
  const int p = blockIdx.x * 256 + threadIdx.x;   // 0..kPlane-1
  if (p == 0) out[0] = 0.0f;
  const int cloud = p >> 12, q = p & (kN - 1);
  const int stg = q >> 8, pl = q & (kStage - 1);
  // u16 units: cloud 65536 (128KB), stage 4096 (8KB), khalf 2048 (4KB)
  const size_t boff = (size_t)cloud * 65536 + (size_t)stg * 4096 + (size_t)pl * 8;
  const u16 one = 0x3F80;

  const float* srcs[2] = {pred, targ};
  u16* adsts[2] = {Apred, Atarg};
  u16* bdsts[2] = {Bpred, Btarg};
#pragma unroll
  for (int which = 0; which < 2; ++which) {
    const float a = srcs[which][3 * p], c = srcs[which][3 * p + 1],
                d = srcs[which][3 * p + 2];
    const u16 ah = bf16_rn(a), ch = bf16_rn(c), dh = bf16_rn(d);
    const u16 al = bf16_rn(a - bf16_f(ah));
    const u16 cl = bf16_rn(c - bf16_f(ch));
    const u16 dl = bf16_rn(d - bf16_f(dh));
    const float s2 = fmaf(a, a, fmaf(c, c, d * d));
    const u16 s2h = bf16_rn(s2);
    const u16 s2l = bf16_rn(s2 - bf16_f(s2h));
    {  // A row: k 0-2 xh, 3-5 xl, 6-8 xh, 9 x2h, 10 x2l, 11 1, 12 1, 13-15 xl
      uint4 w0, w1;
      w0.x = pk2(ah, ch); w0.y = pk2(dh, al); w0.z = pk2(cl, dl); w0.w = pk2(ah, ch);
      w1.x = pk2(dh, s2h); w1.y = pk2(s2l, one); w1.z = pk2(one, al); w1.w = pk2(cl, dl);
      uint4* dst = reinterpret_cast<uint4*>(adsts[which] + (size_t)p * 16);
      dst[0] = w0; dst[1] = w1;
    }
    {  // B row: k 0-2 -2yh, 3-5 -2yh, 6-8 -2yl, 9 1, 10 1, 11 y2h, 12 y2l,
       //        13-15 -2yl  (-2 scale exact in bf16)
      const u16 nah = bf16_rn(-2.0f * bf16_f(ah));
      const u16 nch = bf16_rn(-2.0f * bf16_f(ch));
      const u16 ndh = bf16_rn(-2.0f * bf16_f(dh));
      const u16 nal = bf16_rn(-2.0f * bf16_f(al));
      const u16 ncl = bf16_rn(-2.0f * bf16_f(cl));
      const u16 ndl = bf16_rn(-2.0f * bf16_f(dl));
      uint4 w0, w1;
      w0.x = pk2(nah, nch); w0.y = pk2(ndh, nah); w0.z = pk2(nch, ndh); w0.w = pk2(nal, ncl);
      w1.x = pk2(ndl, one); w1.y = pk2(one, s2h); w1.z = pk2(s2l, nal); w1.w = pk2(ncl, ndl);
      *reinterpret_cast<uint4*>(bdsts[which] + boff) = w0;
      *reinterpret_cast<uint4*>(bdsts[which] + boff + 2048) = w1;
    }
  }
}

// Block = 4 waves x 32 rows = 128 rows of X (cloud, chunk); scans its
// 2048-point j-slice staged through double-buffered LDS (16KB total).
// 32x32x16: A lane l31 -> row, half=lane>>5 -> k-half; B lane l31 -> col.
// C/D [m74/m101, R8-proven]: col=lane&31, row=(reg&3)+8*(reg>>2)+4*half.
// Slice-partial row-mins -> 32-lane butterfly -> rowpart (plain stores).
__global__ __launch_bounds__(256) void cd_mfma(
    const u16* __restrict__ Apred, const u16* __restrict__ Atarg,
    const u16* __restrict__ Bpred, const u16* __restrict__ Btarg,
    float* __restrict__ rowpart) {
  __shared__ uint4 Blds4[1024];   // 16 KB: double-buffered stage (2 x 8 KB)

  const int t = threadIdx.x;
  const int w = t >> 6, lane = t & 63;
  const int half = lane >> 5, l31 = lane & 31;
  const int bx = blockIdx.x;
  const int chunk = bx & 31;         // 0..31 -> 128 rows per block
  const int slice = bx >> 5;         // 0..kJS-1
  const int cloud = blockIdx.y;      // 0..15
  const int dir = blockIdx.z;        // 0: pred rows vs targ; 1: swapped
  const u16* __restrict__ A = dir ? Atarg : Apred;
  const u16* __restrict__ B = dir ? Bpred : Btarg;

  // ---- A fragment: lane holds A[row = band+l31][k = half*8 .. +7] ----
  const int arow = cloud * kN + chunk * 128 + w * 32 + l31;
  union U { uint4 u; bf16x8 v; };
  U af;
  af.u = *reinterpret_cast<const uint4*>(A + (size_t)arow * 16 + half * 8);

  // ---- staging: linear copy, 2 x global_load_lds(16B) per thread/stage ----
  // slice base: cloud*128KB + slice*64KB; stage: 8KB
  const char* bsl = (const char*)B + (size_t)cloud * 131072 +
                    (size_t)slice * 65536;
  char* ldsbase = (char*)Blds4;
#define STAGE(st, buf)                                                        \
  {                                                                           \
    const char* _src = bsl + (size_t)(st) * 8192;                             \
    char* _dst = ldsbase + (buf) * 8192;                                      \
    _Pragma("unroll")                                                         \
    for (int i = 0; i < 2; ++i) {                                             \
      __builtin_amdgcn_global_load_lds(                                       \
          (const __attribute__((address_space(1))) void*)(_src +              \
              ((w * 2 + i) * 64 + lane) * 16),                                \
          (__attribute__((address_space(3))) void*)(_dst + (w * 2 + i) * 1024),\
          16, 0, 0);                                                          \
    }                                                                         \
  }

  f32x16 zacc;
#pragma unroll
  for (int r = 0; r < 16; ++r) zacc[r] = 0.0f;
  float rmin[16];
#pragma unroll
  for (int r = 0; r < 16; ++r) rmin[r] = 1e30f;

  STAGE(0, 0);
  __syncthreads();   // buf0 ready

  for (int st = 0; st < kNS; ++st) {
    if (st < kNS - 1) STAGE(st + 1, (st + 1) & 1);
    // read base: buffer + k-half plane (4KB) + own column slot
    const char* hb = ldsbase + (st & 1) * 8192 + half * 4096 + l31 * 16;
#pragma unroll
    for (int jt = 0; jt < kStage / 64; ++jt) {   // 4 iters, 64 j each
      U b0, b1;
      b0.u = *reinterpret_cast<const uint4*>(hb + jt * 1024);
      b1.u = *reinterpret_cast<const uint4*>(hb + jt * 1024 + 512);
      const f32x16 s0 =
          __builtin_amdgcn_mfma_f32_32x32x16_bf16(af.v, b0.v, zacc, 0, 0, 0);
      const f32x16 s1 =
          __builtin_amdgcn_mfma_f32_32x32x16_bf16(af.v, b1.v, zacc, 0, 0, 0);
#pragma unroll
      for (int r = 0; r < 16; ++r)
        asm("v_min3_f32 %0, %0, %1, %2"
            : "+v"(rmin[r]) : "v"(s0[r]), "v"(s1[r]));
    }
    __syncthreads();   // stage loads landed; compute done before overwrite
  }
#undef STAGE

  // Complete slice row-mins: butterfly across the 32 lanes of each half.
#pragma unroll
  for (int sh = 1; sh < 32; sh <<= 1) {
#pragma unroll
    for (int r = 0; r < 16; ++r)
      rmin[r] = fminf(rmin[r], __shfl_xor(rmin[r], sh, 64));
  }
  if (l31 == 0) {   // lanes 0 and 32: each holds its half's 16 row-mins
    float* rp = rowpart + (((size_t)dir * kJS + slice) * kB + cloud) * kN +
                chunk * 128 + w * 32;
#pragma unroll
    for (int r = 0; r < 16; ++r) {
      const int row = (r & 3) + 8 * (r >> 2) + 4 * half;
      rp[row] = rmin[r];
    }
  }
}

// Per (dir, cloud, row): min over kJS slice-partials; block-sum -> atomicAdd.
__global__ __launch_bounds__(256) void cd_reduce(
    const float* __restrict__ rowpart, float* __restrict__ out) {
  const int u = blockIdx.x * 256 + threadIdx.x;   // 0..2*kPlane-1
  const int dir = u >> 16, rest = u & 65535;
  const int cloud = rest >> 12, row = rest & (kN - 1);
  float rm = 1e30f;
#pragma unroll
  for (int s2 = 0; s2 < kJS; ++s2)
    rm = fminf(rm, rowpart[(((size_t)dir * kJS + s2) * kB + cloud) * kN + row]);
  float s = rm;
  for (int o = 32; o > 0; o >>= 1) s += __shfl_down(s, o, 64);
  __shared__ float wsum[4];
  const int lane = threadIdx.x & 63, wv = threadIdx.x >> 6;
  if (lane == 0) wsum[wv] = s;
  __syncthreads();
  if (threadIdx.x == 0)
    atomicAdd(out, (wsum[0] + wsum[1] + wsum[2] + wsum[3]) * kScale);
}

// ---------- fallback (small ws): R5-style pk_fma direct kernel ----------
template <int KX>
__global__ __launch_bounds__(256) void chamfer_direct(
    const float* __restrict__ pred, const float* __restrict__ targ,
    float* __restrict__ out) {
  __shared__ float4 tA[128], tB[128];
  const int t = threadIdx.x;
  const int xb = blockIdx.x, b = blockIdx.y, dir = blockIdx.z;
  const float* __restrict__ X = dir ? targ : pred;
  const float* __restrict__ Y = dir ? pred : targ;
  float2 xx2[KX], xy2[KX], xz2[KX];
  float x2[KX], mn[KX];
  const int ibase = b * kN + xb * (256 * KX) + t;
#pragma unroll
  for (int k = 0; k < KX; ++k) {
    const int i = ibase + k * 256;
    const float a = X[3 * i], c = X[3 * i + 1], d = X[3 * i + 2];
    x2[k] = fmaf(a, a, fmaf(c, c, d * d));
    xx2[k] = make_float2(-2.0f * a, -2.0f * a);
    xy2[k] = make_float2(-2.0f * c, -2.0f * c);
    xz2[k] = make_float2(-2.0f * d, -2.0f * d);
    mn[k] = 1e30f;
  }
  for (int t0 = 0; t0 < kN; t0 += 256) {
    __syncthreads();
    if (t < 128) {
      const int j0 = 3 * (b * kN + t0 + 2 * t);
      const float a0 = Y[j0], c0 = Y[j0 + 1], d0 = Y[j0 + 2];
      const float a1 = Y[j0 + 3], c1 = Y[j0 + 4], d1 = Y[j0 + 5];
      tA[t] = make_float4(a0, a1, c0, c1);
      tB[t] = make_float4(d0, d1, fmaf(a0, a0, fmaf(c0, c0, d0 * d0)),
                          fmaf(a1, a1, fmaf(c1, c1, d1 * d1)));
    }
    __syncthreads();
    for (int jj = 0; jj < 128; ++jj) {
      const float4 qa = tA[jj], qb = tB[jj];
      const float2 qx = make_float2(qa.x, qa.y), qy = make_float2(qa.z, qa.w);
      const float2 qz = make_float2(qb.x, qb.y), qw = make_float2(qb.z, qb.w);
#pragma unroll
      for (int k = 0; k < KX; ++k) {
        float2 acc;
        asm("v_pk_fma_f32 %0, %1, %2, %3\n\t"
            "v_pk_fma_f32 %0, %4, %5, %0\n\t"
            "v_pk_fma_f32 %0, %6, %7, %0"
            : "=&v"(acc)
            : "v"(xz2[k]), "v"(qz), "v"(qw), "v"(xy2[k]), "v"(qy),
              "v"(xx2[k]), "v"(qx));
        asm("v_min3_f32 %0, %0, %1, %2" : "+v"(mn[k]) : "v"(acc.x), "v"(acc.y));
      }
    }
  }
  float s = 0.0f;
#pragma unroll
  for (int k = 0; k < KX; ++k) s += x2[k] + mn[k];
  for (int o = 32; o > 0; o >>= 1) s += __shfl_down(s, o, 64);
  __shared__ float wsum[4];
  const int lane = t & 63, wv = t >> 6;
  if (lane == 0) wsum[wv] = s;
  __syncthreads();
  if (t == 0)
    atomicAdd(out, (wsum[0] + wsum[1] + wsum[2] + wsum[3]) * kScale);
}

}  // namespace

extern "C" void kernel_launch(void* const* d_in, const int* in_sizes, int n_in,
                              void* d_out, int out_size, void* d_ws,
                              size_t ws_size, hipStream_t stream) {
  const float* pred = (const float*)d_in[0];
  const float* targ = (const float*)d_in[1];
  float* out = (float*)d_out;

  const size_t needOne = (size_t)kPlane * 16 * sizeof(u16);        // 2 MB each
  const size_t needRow = (size_t)2 * kJS * kB * kN * sizeof(float);  // 1 MB
  if (ws_size >= 4 * needOne + needRow) {                          // 9 MB
    u16* Apred = (u16*)d_ws;
    u16* Atarg = (u16*)((char*)d_ws + needOne);
    u16* Bpred = (u16*)((char*)d_ws + 2 * needOne);
    u16* Btarg = (u16*)((char*)d_ws + 3 * needOne);
    float* rowpart = (float*)((char*)d_ws + 4 * needOne);
    cd_prep<<<dim3(kPlane / 256), 256, 0, stream>>>(pred, targ, Apred, Atarg,
                                                    Bpred, Btarg, out);
    cd_mfma<<<dim3(32 * kJS, kB, 2), 256, 0, stream>>>(Apred, Atarg, Bpred,
                                                       Btarg, rowpart);
    cd_reduce<<<dim3(2 * kPlane / 256), 256, 0, stream>>>(rowpart, out);
  } else {
    init_out<<<dim3(1), dim3(1), 0, stream>>>(out);
    constexpr int KX = 8;
    dim3 grid(kN / (256 * KX), kB, 2);
    chamfer_direct<KX><<<grid, 256, 0, stream>>>(pred, targ, out);
  }
}